// Round 1
// baseline (784.807 us; speedup 1.0000x reference)
//
#include <hip/hip_runtime.h>

// Problem constants
#define BB 64
#define TT 2048
#define HH 1024
#define AA 256
// GEMM: M = BB*TT = 131072, N = AA = 256, K = HH = 1024
#define M_TILE 64            // rows per block (one b, 64 consecutive t)
#define N_CHUNKS (TT / M_TILE)  // 32 chunks per batch
#define NBLK (BB * TT / M_TILE) // 2048 blocks
#define KSTEPS (HH / 32)        // 32 k-steps of 32

typedef __attribute__((ext_vector_type(4))) float f32x4;
typedef __attribute__((ext_vector_type(8))) short s16x8;

__device__ __forceinline__ short f2bf(float f) {
    // round-to-nearest-even fp32 -> bf16 (no NaN inputs here)
    unsigned int u = __float_as_uint(f);
    u += 0x7fffu + ((u >> 16) & 1u);
    return (short)(u >> 16);
}

__device__ __forceinline__ float fast_tanh(float x) {
    // tanh via hardware exp; clamp to avoid inf/inf
    x = fminf(fmaxf(x, -10.f), 10.f);
    float e = __expf(2.f * x);
    return (e - 1.f) / (e + 1.f);
}

__device__ __forceinline__ void gld_lds16(const void* gptr, void* lptr) {
    // async global->LDS, 16 B per lane; LDS dest must be uniform_base + lane*16
    __builtin_amdgcn_global_load_lds(
        (const __attribute__((address_space(1))) unsigned int*)gptr,
        (__attribute__((address_space(3))) unsigned int*)lptr,
        16, 0, 0);
}

// ---------------------------------------------------------------------------
// Kernel 0: convert W [K=1024][N=256] fp32 -> bf16 fragment layout
// wfrag[kk][quad][n][j]  (j in 0..7, k = kk*32 + quad*8 + j), contiguous —
// exactly the LDS image global_load_lds will stage per K-step.
// ---------------------------------------------------------------------------
__global__ __launch_bounds__(256) void wconv_kernel(const float* __restrict__ w,
                                                    short* __restrict__ wfrag) {
    int t = blockIdx.x * 256 + threadIdx.x;   // 0..32767
    int kq = t >> 8;                          // kk*4 + quad, 0..127
    int n  = t & 255;
    int kbase = kq * 8;
    s16x8 o;
#pragma unroll
    for (int j = 0; j < 8; ++j)
        o[j] = f2bf(w[(size_t)(kbase + j) * AA + n]);
    *(s16x8*)(wfrag + (size_t)t * 8) = o;
}

// ---------------------------------------------------------------------------
// Kernel 1: per 64-row tile: scores via MFMA GEMM + tanh·u reduction,
// chunk-local softmax (m_c, l_c), weighted partial sum over the tile's rows.
// ---------------------------------------------------------------------------
__global__ __launch_bounds__(256) void score_pool_kernel(
    const float* __restrict__ X,      // [M][1024] fp32
    const short* __restrict__ wfrag,  // bf16 frags, 512 KB
    const float* __restrict__ bo,     // [256]
    const float* __restrict__ uo,     // [256]
    float* __restrict__ partials,     // [NBLK][1024]
    float* __restrict__ mstats)       // [NBLK][2] = {m_c, l_c}
{
    __shared__ __attribute__((aligned(16))) short lds_a[M_TILE * 40]; // stride 40 pads banks
    __shared__ __attribute__((aligned(16))) short lds_b[4 * 256 * 8]; // [quad][n][8]
    __shared__ float lds_red[4][M_TILE];
    __shared__ float lds_w[M_TILE];

    const int tid  = threadIdx.x;
    const int wave = tid >> 6;
    const int lane = tid & 63;
    const int q    = lane >> 4;  // quad
    const int ln   = lane & 15;
    const size_t m0 = (size_t)blockIdx.x * M_TILE;

    f32x4 acc[4][4];  // [m-tile][n-tile], wave covers all 64 m, n = wave*64..+64
    const f32x4 zero = {0.f, 0.f, 0.f, 0.f};
#pragma unroll
    for (int i = 0; i < 4; ++i)
#pragma unroll
        for (int j = 0; j < 4; ++j) acc[i][j] = zero;

    const int arow = tid >> 2;        // 0..63
    const int akp  = (tid & 3) * 8;   // 0,8,16,24
    const float* aptr = X + (m0 + (size_t)arow) * HH + akp;

    for (int kk = 0; kk < KSTEPS; ++kk) {
        if (kk) __syncthreads();  // previous iteration's readers done
        // stage B tile (16 KB) via async global->LDS, exact image order
#pragma unroll
        for (int it = 0; it < 4; ++it) {
            int u = it * 256 + tid;
            gld_lds16(wfrag + (size_t)kk * 8192 + (size_t)u * 8, &lds_b[u * 8]);
        }
        // stage A tile: 8 fp32 per thread -> bf16 -> LDS (padded stride)
        const float4* ap = (const float4*)(aptr + kk * 32);
        float4 x0 = ap[0];
        float4 x1 = ap[1];
        s16x8 av;
        av[0] = f2bf(x0.x); av[1] = f2bf(x0.y); av[2] = f2bf(x0.z); av[3] = f2bf(x0.w);
        av[4] = f2bf(x1.x); av[5] = f2bf(x1.y); av[6] = f2bf(x1.z); av[7] = f2bf(x1.w);
        *(s16x8*)&lds_a[arow * 40 + akp] = av;
        __syncthreads();  // waits vmcnt(0): global_load_lds complete too

        s16x8 af[4], bf[4];
#pragma unroll
        for (int mt = 0; mt < 4; ++mt)
            af[mt] = *(const s16x8*)&lds_a[(mt * 16 + ln) * 40 + q * 8];
#pragma unroll
        for (int nt = 0; nt < 4; ++nt)
            bf[nt] = *(const s16x8*)&lds_b[q * 2048 + (wave * 64 + nt * 16 + ln) * 8];
#pragma unroll
        for (int mt = 0; mt < 4; ++mt)
#pragma unroll
            for (int nt = 0; nt < 4; ++nt)
                acc[mt][nt] = __builtin_amdgcn_mfma_f32_16x16x32_bf16(
                    af[mt], bf[nt], acc[mt][nt], 0, 0, 0);
    }

    // ---- epilogue: scores = sum_n tanh(acc + b[n]) * u[n] ----
    float bv[4], uv[4];
#pragma unroll
    for (int nt = 0; nt < 4; ++nt) {
        int n = wave * 64 + nt * 16 + ln;
        bv[nt] = bo[n];
        uv[nt] = uo[n];
    }
    float s[4][4];
#pragma unroll
    for (int mt = 0; mt < 4; ++mt) {
#pragma unroll
        for (int r = 0; r < 4; ++r) {
            float v = 0.f;
#pragma unroll
            for (int nt = 0; nt < 4; ++nt) {
                float p = acc[mt][nt][r] + bv[nt];
                v += fast_tanh(p) * uv[nt];
            }
            // reduce over the 16 lanes (n within group); stays inside group
            v += __shfl_xor(v, 1);
            v += __shfl_xor(v, 2);
            v += __shfl_xor(v, 4);
            v += __shfl_xor(v, 8);
            s[mt][r] = v;
        }
    }
    if (ln == 0) {
#pragma unroll
        for (int mt = 0; mt < 4; ++mt)
#pragma unroll
            for (int r = 0; r < 4; ++r)
                lds_red[wave][mt * 16 + q * 4 + r] = s[mt][r];
    }
    __syncthreads();

    // ---- chunk-local softmax over the 64 rows (wave 0 only) ----
    if (tid < 64) {
        float sv = lds_red[0][tid] + lds_red[1][tid] + lds_red[2][tid] + lds_red[3][tid];
        float mx = sv;
        mx = fmaxf(mx, __shfl_xor(mx, 1));
        mx = fmaxf(mx, __shfl_xor(mx, 2));
        mx = fmaxf(mx, __shfl_xor(mx, 4));
        mx = fmaxf(mx, __shfl_xor(mx, 8));
        mx = fmaxf(mx, __shfl_xor(mx, 16));
        mx = fmaxf(mx, __shfl_xor(mx, 32));
        float wv = __expf(sv - mx);
        float ls = wv;
        ls += __shfl_xor(ls, 1);
        ls += __shfl_xor(ls, 2);
        ls += __shfl_xor(ls, 4);
        ls += __shfl_xor(ls, 8);
        ls += __shfl_xor(ls, 16);
        ls += __shfl_xor(ls, 32);
        lds_w[tid] = wv;
        if (tid == 0) {
            mstats[2 * blockIdx.x]     = mx;
            mstats[2 * blockIdx.x + 1] = ls;
        }
    }
    __syncthreads();

    // ---- weighted partial sum over this tile's 64 rows (L2/L3-hot re-read) ----
    float4 o = {0.f, 0.f, 0.f, 0.f};
    const float* xb = X + m0 * HH + tid * 4;
#pragma unroll 4
    for (int t = 0; t < M_TILE; ++t) {
        float wt = lds_w[t];
        float4 xv = *(const float4*)(xb + (size_t)t * HH);
        o.x += wt * xv.x;
        o.y += wt * xv.y;
        o.z += wt * xv.z;
        o.w += wt * xv.w;
    }
    *(float4*)(partials + (size_t)blockIdx.x * HH + tid * 4) = o;
}

// ---------------------------------------------------------------------------
// Kernel 2: combine 32 chunks per batch with global rescaling, write output
// row [1024 pooled + 1.0 pad column].
// ---------------------------------------------------------------------------
__global__ __launch_bounds__(256) void combine_kernel(
    const float* __restrict__ partials,
    const float* __restrict__ mstats,
    float* __restrict__ out)
{
    int b = blockIdx.x;
    int tid = threadIdx.x;
    float M = -1e30f;
#pragma unroll
    for (int c = 0; c < N_CHUNKS; ++c)
        M = fmaxf(M, mstats[2 * (b * N_CHUNKS + c)]);
    float denom = 0.f;
    float4 o = {0.f, 0.f, 0.f, 0.f};
    for (int c = 0; c < N_CHUNKS; ++c) {
        int ch = b * N_CHUNKS + c;
        float sc = __expf(mstats[2 * ch] - M);
        denom += sc * mstats[2 * ch + 1];
        float4 p = *(const float4*)(partials + (size_t)ch * HH + tid * 4);
        o.x += sc * p.x;
        o.y += sc * p.y;
        o.z += sc * p.z;
        o.w += sc * p.w;
    }
    float inv = 1.f / denom;
    float* orow = out + (size_t)b * (HH + 1) + tid * 4;  // row stride 1025: scalar stores
    orow[0] = o.x * inv;
    orow[1] = o.y * inv;
    orow[2] = o.z * inv;
    orow[3] = o.w * inv;
    if (tid == 0) out[(size_t)b * (HH + 1) + HH] = 1.0f;
}

// ---------------------------------------------------------------------------
extern "C" void kernel_launch(void* const* d_in, const int* in_sizes, int n_in,
                              void* d_out, int out_size, void* d_ws, size_t ws_size,
                              hipStream_t stream) {
    const float* X  = (const float*)d_in[0];  // [64,2048,1024]
    const float* w  = (const float*)d_in[1];  // [1024,256]
    const float* bo = (const float*)d_in[2];  // [256]
    const float* uo = (const float*)d_in[3];  // [256]
    float* out = (float*)d_out;               // [64,1025]

    char* ws = (char*)d_ws;
    short* wfrag    = (short*)ws;                                  // 512 KB
    float* partials = (float*)(ws + (512u << 10));                 // 8 MB
    float* mstats   = (float*)(ws + (512u << 10) + (8u << 20));    // 16 KB

    wconv_kernel<<<128, 256, 0, stream>>>(w, wfrag);
    score_pool_kernel<<<NBLK, 256, 0, stream>>>(X, wfrag, bo, uo, partials, mstats);
    combine_kernel<<<BB, 256, 0, stream>>>(partials, mstats, out);
}